// Round 20
// baseline (90.848 us; speedup 1.0000x reference)
//
#include <hip/hip_runtime.h>
#include <hip/hip_bf16.h>

#define BATCH 32768
#define NPAIR 64
#define NBLK  128

typedef __bf16 bf16x8 __attribute__((ext_vector_type(8)));
typedef float  f32x4  __attribute__((ext_vector_type(4)));
typedef float  f32x4e __attribute__((ext_vector_type(4)));
static_assert(sizeof(bf16x8) == 16, "bf16x8 must be 16B");

// ---- workspace byte offsets ----
#define WS_CNT      0
#define WS_BASE     256
#define WS_BH       1024
#define WS_PAIR     66560
#define WS_ROWLIST  197632
#define WS_WF00     336896     /* frag-major [m][NT16][KC2][64]x16B = 32KB/m */
#define WS_WF01     599040     /* [m][NT8][KC8][64] = 64KB/m */
#define WS_WF1P     1123328    /* 32KB/m */
#define WS_WF1A     1385472    /* [m][NT8][KC12][64] = 96KB/m */
#define WS_WF1O     2171904    /* [m][NT2][KC4][64] = 8KB/m */

__device__ __forceinline__ unsigned short f2bf(float x) {
  __bf16 h = (__bf16)x;
  return __builtin_bit_cast(unsigned short, h);
}

#define KEEP(x) asm volatile("" : "+v"(x))

// Blocks 0..239: weight fp32 -> bf16 MFMA-fragment-major. Blocks 240..367: route.
__global__ __launch_bounds__(256) void k_combo(const float* __restrict__ w00,
                                               const float* __restrict__ w01,
                                               const float* __restrict__ w1p,
                                               const float* __restrict__ w1a,
                                               const float* __restrict__ w1o,
                                               const float* __restrict__ inp,
                                               char* __restrict__ ws) {
  __shared__ unsigned short lds[64 * 72];
  int bid = blockIdx.x;
  if (bid >= 240) {
    int* h = (int*)lds;
    int rbid = bid - 240;
    int t = threadIdx.x;
    if (t < NPAIR) h[t] = 0;
    __syncthreads();
    int r = rbid * 256 + t;
    const float* q = inp + (size_t)r * 144 + 128;
    float4 u0 = *(const float4*)(q + 0);
    float4 u1 = *(const float4*)(q + 4);
    float4 v0 = *(const float4*)(q + 8);
    float4 v1 = *(const float4*)(q + 12);
    int a0 = 0;
    if (u0.y > 0.5f) a0 = 1; if (u0.z > 0.5f) a0 = 2; if (u0.w > 0.5f) a0 = 3;
    if (u1.x > 0.5f) a0 = 4; if (u1.y > 0.5f) a0 = 5; if (u1.z > 0.5f) a0 = 6; if (u1.w > 0.5f) a0 = 7;
    int a1 = 0;
    if (v0.y > 0.5f) a1 = 1; if (v0.z > 0.5f) a1 = 2; if (v0.w > 0.5f) a1 = 3;
    if (v1.x > 0.5f) a1 = 4; if (v1.y > 0.5f) a1 = 5; if (v1.z > 0.5f) a1 = 6; if (v1.w > 0.5f) a1 = 7;
    int p = a0 * 8 + a1;
    ((int*)(ws + WS_PAIR))[r] = p;
    atomicAdd(&h[p], 1);
    __syncthreads();
    if (t < NPAIR) ((int*)(ws + WS_BH))[rbid * NPAIR + t] = h[t];
    return;
  }
  const float* src; char* dst; int I, O, lt, NT, KC;
  if (bid < 32)       { src = w00; dst = ws + WS_WF00; I = 64;  O = 256; lt = bid;       NT = 16; KC = 2; }
  else if (bid < 96)  { src = w01; dst = ws + WS_WF01; I = 256; O = 128; lt = bid - 32;  NT = 8;  KC = 8; }
  else if (bid < 128) { src = w1p; dst = ws + WS_WF1P; I = 64;  O = 256; lt = bid - 96;  NT = 16; KC = 2; }
  else if (bid < 224) { src = w1a; dst = ws + WS_WF1A; I = 384; O = 128; lt = bid - 128; NT = 8;  KC = 12; }
  else                { src = w1o; dst = ws + WS_WF1O; I = 128; O = 32;  lt = bid - 224; NT = 2;  KC = 4; }
  int tI = I >> 6;
  int tO = (O + 63) >> 6;
  int m   = lt / (tI * tO);
  int rem = lt % (tI * tO);
  int ib = rem / tO, ob = rem % tO;
  int tx = threadIdx.x & 63, ty = threadIdx.x >> 6;
  const float* s = src + (size_t)m * I * O;
  #pragma unroll 4
  for (int s4 = 0; s4 < 16; ++s4) {
    int li = s4 * 4 + ty;
    int o  = ob * 64 + tx;
    float v = (o < O) ? s[(size_t)(ib * 64 + li) * O + o] : 0.f;
    lds[li * 72 + tx] = f2bf(v);
  }
  __syncthreads();
  int lane = threadIdx.x & 63, u = threadIdx.x >> 6;
  int ln = lane & 15, lq = lane >> 4;
  #pragma unroll
  for (int it = 0; it < 2; ++it) {
    int fi  = it * 4 + u;
    int ntl = fi >> 1, kcl = fi & 1;
    int ntg = ob * 4 + ntl, kcg = ib * 2 + kcl;
    if (ntg * 16 < O) {
      bf16x8 f;
      #pragma unroll
      for (int j = 0; j < 8; ++j)
        f[j] = __builtin_bit_cast(__bf16, lds[(kcl * 32 + lq * 8 + j) * 72 + ntl * 16 + ln]);
      *(bf16x8*)(dst + (((size_t)(m * NT + ntg) * KC + kcg) * 64 + lane) * 16) = f;
    }
  }
}

// k_part: scan (redundant per block, from bh in LDS) + scatter in ONE kernel.
__global__ __launch_bounds__(256) void k_part(const int* __restrict__ bh,
                                              const int* __restrict__ pairArr,
                                              int* __restrict__ cnt,
                                              int* __restrict__ base,
                                              int* __restrict__ rowlist) {
  __shared__ int lbh[NBLK * NPAIR];
  __shared__ int loff[NPAIR];
  __shared__ int h[NPAIR];
  int tid = threadIdx.x, bid = blockIdx.x;
  const int4* s4 = (const int4*)bh;
  int4* d4 = (int4*)lbh;
  #pragma unroll
  for (int i = 0; i < 8; ++i) d4[tid + i * 256] = s4[tid + i * 256];
  if (tid < NPAIR) h[tid] = 0;
  __syncthreads();
  if (tid < NPAIR) {
    int c = 0, partial = 0;
    for (int b = 0; b < NBLK; ++b) {
      int v = lbh[b * NPAIR + tid];
      if (b < bid) partial += v;
      c += v;
    }
    int ntp = (c + 31) >> 5;
    int z = ntp;
    #pragma unroll
    for (int d = 1; d < 64; d <<= 1) { int y = __shfl_up(z, d); if (tid >= d) z += y; }
    int pbase = (z - ntp) * 32;
    loff[tid] = pbase + partial;
    if (bid == 0) { cnt[tid] = c; base[tid] = pbase; }
  }
  __syncthreads();
  int r = bid * 256 + tid;
  int p = pairArr[r];
  int rank = atomicAdd(&h[p], 1);
  rowlist[loff[p] + rank] = r;
}

// Fused 5-layer routed MLP, per-pair persistent, 32-row tiles, 8 waves,
// grid 512 = 64 pairs x 8 slices. LDS 80K EXACTLY -> 2 blocks/CU (4 waves/SIMD):
// W1a kc<4 32K @0, G 16K @32768, H1 16K @49152, HO/G2 shared 8K @65536,
// xs 8K @73728. W00/W1p/W1a-hi(kc>=4) in regs (64 VGPR KEEP). wc/wo at-use.
// R19's P2+P3g overlap kept (G-half of L1a now pure-reg B operands).
// 4 barriers/tile (extra barE guards the HO->G2 alias).
__global__ __launch_bounds__(512, 4) void k_fused(
    const float* __restrict__ inp,
    const float* __restrict__ b00, const float* __restrict__ b01,
    const float* __restrict__ b1p, const float* __restrict__ b1a,
    const float* __restrict__ b1o,
    const char* __restrict__ ws, float* __restrict__ out)
{
  __shared__ char smem[81920];
  unsigned short* G   = (unsigned short*)(smem + 32768);
  unsigned short* H1m = (unsigned short*)(smem + 49152);
  unsigned short* HO  = (unsigned short*)(smem + 65536);
  unsigned short* G2  = (unsigned short*)(smem + 65536);  // aliases HO (barE-guarded)
  char*           xs  = smem + 73728;

  int p     = blockIdx.x >> 3;
  int slice = blockIdx.x & 7;
  int e0 = p >> 3, e1 = p & 7;
  int cnt = ((const int*)(ws + WS_CNT))[p];
  int pbase = ((const int*)(ws + WS_BASE))[p];
  int ntp = (cnt + 31) >> 5;
  if (slice >= ntp) return;
  const int* rlbase = (const int*)(ws + WS_ROWLIST) + pbase;

  int tid  = threadIdx.x;
  // stage W1a[e1] kc<4 (32KB): LDS frag (w2*4+kc) <- global frag (w2*12+kc)
  {
    const f32x4e* s1 = (const f32x4e*)(ws + WS_WF1A + (size_t)e1 * 98304);
    f32x4e* d1 = (f32x4e*)smem;
    #pragma unroll
    for (int i = 0; i < 4; ++i) {
      int fidx = tid + i * 512;          // 0..2047
      int chunk = fidx >> 6, within = fidx & 63;
      int w2 = chunk >> 2, kc = chunk & 3;
      d1[fidx] = s1[(w2 * 12 + kc) * 64 + within];
    }
  }

  int lane = tid & 63;
  int w    = tid >> 6;
  int ln = lane & 15, lq = lane >> 4;
  int kcol = lq * 8;

  // register weight sets (frag-major, lane-contiguous, loaded ONCE)
  bf16x8 w00f[2][2], w1pf[2][2];
  #pragma unroll
  for (int nt = 0; nt < 2; ++nt)
    #pragma unroll
    for (int kc = 0; kc < 2; ++kc) {
      w00f[nt][kc] = *(const bf16x8*)(ws + WS_WF00 + (size_t)e0 * 32768 +
                                      ((((w * 2 + nt) * 2 + kc) * 64 + lane) << 4));
      w1pf[nt][kc] = *(const bf16x8*)(ws + WS_WF1P + (size_t)e1 * 32768 +
                                      ((((w * 2 + nt) * 2 + kc) * 64 + lane) << 4));
    }
  bf16x8 wa_hi[8];   // W1a kc 4..11 (the G-half consumed by P3g)
  #pragma unroll
  for (int j = 0; j < 8; ++j)
    wa_hi[j] = *(const bf16x8*)(ws + WS_WF1A + (size_t)e1 * 98304 +
                                (((w * 12 + 4 + j) * 64 + lane) << 4));
  #pragma unroll
  for (int nt = 0; nt < 2; ++nt)
    #pragma unroll
    for (int kc = 0; kc < 2; ++kc) { KEEP(w00f[nt][kc]); KEEP(w1pf[nt][kc]); }
  #pragma unroll
  for (int j = 0; j < 8; ++j) KEEP(wa_hi[j]);

  float bias00[2], bias1p[2];
  #pragma unroll
  for (int nt = 0; nt < 2; ++nt) {
    bias00[nt] = b00[e0 * 256 + w * 32 + nt * 16 + ln];
    bias1p[nt] = b1p[e1 * 256 + w * 32 + nt * 16 + ln];
  }
  float bias01 = b01[e0 * 128 + w * 16 + ln];
  float bias1a = b1a[e1 * 128 + w * 16 + ln];
  float bias1o = (w < 4) ? b1o[e1 * 32 + (w >> 1) * 16 + ln] : 0.f;

  const f32x4 z4 = {0.f, 0.f, 0.f, 0.f};
  int srow = tid >> 5, scol = tid & 31;    // staging: 16 rows/pass, 32 float4/row

  // ---- prologue: stage first tile directly into xs ----
  {
    int nr0 = min(32, cnt - slice * 32);
    const int* rl0 = rlbase + slice * 32;
    #pragma unroll
    for (int pass = 0; pass < 2; ++pass) {
      int row = pass * 16 + srow;
      int rg = (row < nr0) ? rl0[row] : -1;
      ushort4 v8 = {0, 0, 0, 0};
      if (rg >= 0) {
        f32x4e u = __builtin_nontemporal_load(
            (const f32x4e*)(inp + (size_t)rg * 144 + scol * 4));
        v8.x = f2bf(u.x); v8.y = f2bf(u.y); v8.z = f2bf(u.z); v8.w = f2bf(u.w);
      }
      int byte = (row * 256 + scol * 8) ^ ((row & 7) << 4);
      *(ushort4*)(xs + byte) = v8;
    }
  }
  __syncthreads();  // W1a staged + first xs ready

  for (int t = slice; t < ntp; t += 8) {
    int nr = min(32, cnt - t * 32);
    const int* rl = rlbase + t * 32;

    // ---- issue next tile's stage loads NOW (hidden under P1) ----
    int t2 = t + 8;
    bool hasNext = (t2 < ntp);
    f32x4e pre[2];
    #pragma unroll
    for (int pass = 0; pass < 2; ++pass) { pre[pass].x = 0; pre[pass].y = 0; pre[pass].z = 0; pre[pass].w = 0; }
    if (hasNext) {
      int nr2 = min(32, cnt - t2 * 32);
      const int* rl2 = rlbase + t2 * 32;
      #pragma unroll
      for (int pass = 0; pass < 2; ++pass) {
        int row = pass * 16 + srow;
        int rg = (row < nr2) ? rl2[row] : -1;
        if (rg >= 0)
          pre[pass] = __builtin_nontemporal_load(
              (const f32x4e*)(inp + (size_t)rg * 144 + scol * 4));
      }
      KEEP(pre[0]); KEEP(pre[1]);
    }

    // ===== P1: L00 -> H1, L1p -> G (reg weights, xs frags) =====
    bf16x8 axf[2][2][2];   // [half][mt][kc]
    #pragma unroll
    for (int half = 0; half < 2; ++half)
      #pragma unroll
      for (int mt = 0; mt < 2; ++mt)
        #pragma unroll
        for (int kc = 0; kc < 2; ++kc) {
          int row = mt * 16 + ln;
          int byte = (row * 256 + half * 128 + kc * 64 + lq * 16) ^ ((row & 7) << 4);
          axf[half][mt][kc] = *(const bf16x8*)(xs + byte);
        }
    #pragma unroll
    for (int nt = 0; nt < 2; ++nt) {
      int n = w * 32 + nt * 16 + ln;
      f32x4 acc0[2] = {z4, z4}, acc1[2] = {z4, z4};
      #pragma unroll
      for (int kc = 0; kc < 2; ++kc)
        #pragma unroll
        for (int mt = 0; mt < 2; ++mt) {
          acc0[mt] = __builtin_amdgcn_mfma_f32_16x16x32_bf16(axf[0][mt][kc], w00f[nt][kc], acc0[mt], 0, 0, 0);
          acc1[mt] = __builtin_amdgcn_mfma_f32_16x16x32_bf16(axf[1][mt][kc], w1pf[nt][kc], acc1[mt], 0, 0, 0);
        }
      #pragma unroll
      for (int mt = 0; mt < 2; ++mt)
        #pragma unroll
        for (int r = 0; r < 4; ++r) {
          int row = mt * 16 + lq * 4 + r;
          int sw = ((n << 1) ^ ((row & 7) << 4));
          H1m[(row * 512 + sw) >> 1] = f2bf(fmaxf(acc0[mt][r] + bias00[nt], 0.f));
          G  [(row * 512 + sw) >> 1] = f2bf(fmaxf(acc1[mt][r] + bias1p[nt], 0.f));
        }
    }
    __syncthreads();  // barB: H1,G ready; all xs reads done

    // ---- write next tile's xs from prefetched regs ----
    if (hasNext) {
      #pragma unroll
      for (int pass = 0; pass < 2; ++pass) {
        int row = pass * 16 + srow;
        ushort4 v8;
        v8.x = f2bf(pre[pass].x); v8.y = f2bf(pre[pass].y);
        v8.z = f2bf(pre[pass].z); v8.w = f2bf(pre[pass].w);
        int byte = (row * 256 + scol * 8) ^ ((row & 7) << 4);
        *(ushort4*)(xs + byte) = v8;
      }
    }

    // ===== P2 + P3g (overlapped): L01(H1) -> HO, and L1a G-half (reg B) =====
    f32x4 acc1a[2] = {z4, z4};   // persists across barC
    {
      f32x4 acc[2] = {z4, z4};
      #pragma unroll
      for (int kc = 0; kc < 8; ++kc) {
        bf16x8 bfr01 = *(const bf16x8*)(ws + WS_WF01 + (size_t)e0 * 65536 +
                                        (((w * 8 + kc) * 64 + lane) << 4));
        #pragma unroll
        for (int mt = 0; mt < 2; ++mt) {
          int row = mt * 16 + ln;
          bf16x8 afr = *(const bf16x8*)&H1m[(row * 512 + (((kc * 32 + kcol) << 1) ^ ((row & 7) << 4))) >> 1];
          acc[mt] = __builtin_amdgcn_mfma_f32_16x16x32_bf16(afr, bfr01, acc[mt], 0, 0, 0);
        }
        // L1a G-half chunk (global kc+4), reg B operand
        #pragma unroll
        for (int mt = 0; mt < 2; ++mt) {
          int row = mt * 16 + ln;
          bf16x8 afr = *(const bf16x8*)&G[(row * 512 + (((kc * 32 + kcol) << 1) ^ ((row & 7) << 4))) >> 1];
          acc1a[mt] = __builtin_amdgcn_mfma_f32_16x16x32_bf16(afr, wa_hi[kc], acc1a[mt], 0, 0, 0);
        }
      }
      int n = w * 16 + ln;
      #pragma unroll
      for (int mt = 0; mt < 2; ++mt)
        #pragma unroll
        for (int r = 0; r < 4; ++r) {
          int row = mt * 16 + lq * 4 + r;
          float v = fmaxf(acc[mt][r] + bias01, 0.f);
          HO[(row * 256 + ((n << 1) ^ ((row & 7) << 4))) >> 1] = f2bf(v);
        }
    }
    __syncthreads();  // barC: HO ready

    // ===== P3h: L1a HO-half (kc<4, LDS B) -> finish acc1a; barE; -> G2 =====
    {
      #pragma unroll
      for (int kc = 0; kc < 4; ++kc) {
        bf16x8 bfr = *(const bf16x8*)(smem + (((w * 4 + kc) * 64 + lane) << 4));
        #pragma unroll
        for (int mt = 0; mt < 2; ++mt) {
          int row = mt * 16 + ln;
          bf16x8 afr = *(const bf16x8*)&HO[(row * 256 + (((kc * 32 + kcol) << 1) ^ ((row & 7) << 4))) >> 1];
          acc1a[mt] = __builtin_amdgcn_mfma_f32_16x16x32_bf16(afr, bfr, acc1a[mt], 0, 0, 0);
        }
      }
    }
    __syncthreads();  // barE: all HO reads done; safe to overwrite via G2 alias
    {
      int n = w * 16 + ln;
      #pragma unroll
      for (int mt = 0; mt < 2; ++mt)
        #pragma unroll
        for (int r = 0; r < 4; ++r) {
          int row = mt * 16 + lq * 4 + r;
          float v = fmaxf(acc1a[mt][r] + bias1a, 0.f);
          G2[(row * 256 + ((n << 1) ^ ((row & 7) << 4))) >> 1] = f2bf(v);
        }
    }
    __syncthreads();  // barD: G2 ready

    // ===== P4 (waves 0..3): L1o (G2 @ at-use W1o) -> out (NT store) =====
    if (w < 4) {
      int mt = w & 1;
      int n  = (w >> 1) * 16 + ln;
      f32x4 acc = z4;
      #pragma unroll
      for (int kc = 0; kc < 4; ++kc) {
        int row = mt * 16 + ln;
        bf16x8 afr = *(const bf16x8*)&G2[(row * 256 + (((kc * 32 + kcol) << 1) ^ ((row & 7) << 4))) >> 1];
        bf16x8 bfr = *(const bf16x8*)(ws + WS_WF1O + (size_t)e1 * 8192 +
                                      ((((w >> 1) * 4 + kc) * 64 + lane) << 4));
        acc = __builtin_amdgcn_mfma_f32_16x16x32_bf16(afr, bfr, acc, 0, 0, 0);
      }
      #pragma unroll
      for (int r = 0; r < 4; ++r) {
        int row = mt * 16 + lq * 4 + r;
        if (row < nr) {
          int rg = rl[row];
          __builtin_nontemporal_store(acc[r] + bias1o, &out[(size_t)rg * 32 + n]);
        }
      }
    }
  }
}

extern "C" void kernel_launch(void* const* d_in, const int* in_sizes, int n_in,
                              void* d_out, int out_size, void* d_ws, size_t ws_size,
                              hipStream_t stream) {
  const float* inp = (const float*)d_in[0];
  const float* w00 = (const float*)d_in[1];
  const float* b00 = (const float*)d_in[2];
  const float* w01 = (const float*)d_in[3];
  const float* b01 = (const float*)d_in[4];
  const float* w1p = (const float*)d_in[5];
  const float* b1p = (const float*)d_in[6];
  const float* w1a = (const float*)d_in[7];
  const float* b1a = (const float*)d_in[8];
  const float* w1o = (const float*)d_in[9];
  const float* b1o = (const float*)d_in[10];
  char*  ws  = (char*)d_ws;
  float* out = (float*)d_out;

  k_combo<<<368, 256, 0, stream>>>(w00, w01, w1p, w1a, w1o, inp, ws);
  k_part<<<NBLK, 256, 0, stream>>>((const int*)(ws + WS_BH),
                                   (const int*)(ws + WS_PAIR),
                                   (int*)(ws + WS_CNT), (int*)(ws + WS_BASE),
                                   (int*)(ws + WS_ROWLIST));
  k_fused<<<512, 512, 0, stream>>>(inp, b00, b01, b1p, b1a, b1o, ws, out);
}

// Round 21
// 43.605 us; speedup vs baseline: 2.0834x; 2.0834x over previous
//
#include <hip/hip_runtime.h>
#include <hip/hip_bf16.h>

#define BATCH 32768
#define NPAIR 64
#define NBLK  128

typedef __bf16 bf16x8 __attribute__((ext_vector_type(8)));
typedef float  f32x4  __attribute__((ext_vector_type(4)));
typedef float  f32x4e __attribute__((ext_vector_type(4)));
static_assert(sizeof(bf16x8) == 16, "bf16x8 must be 16B");

// ---- workspace byte offsets ----
#define WS_CNT      0
#define WS_BASE     256
#define WS_BH       1024
#define WS_PAIR     66560
#define WS_ROWLIST  197632
#define WS_WF00     336896     /* frag-major [m][NT16][KC2][64]x16B = 32KB/m */
#define WS_WF01     599040     /* [m][NT8][KC8][64] = 64KB/m */
#define WS_WF1P     1123328    /* 32KB/m */
#define WS_WF1A     1385472    /* [m][NT8][KC12][64] = 96KB/m */
#define WS_WF1O     2171904    /* [m][NT2][KC4][64] = 8KB/m */

__device__ __forceinline__ unsigned short f2bf(float x) {
  __bf16 h = (__bf16)x;
  return __builtin_bit_cast(unsigned short, h);
}

#define KEEP(x) asm volatile("" : "+v"(x))

// Blocks 0..239: weight fp32 -> bf16 MFMA-fragment-major. Blocks 240..367: route.
__global__ __launch_bounds__(256) void k_combo(const float* __restrict__ w00,
                                               const float* __restrict__ w01,
                                               const float* __restrict__ w1p,
                                               const float* __restrict__ w1a,
                                               const float* __restrict__ w1o,
                                               const float* __restrict__ inp,
                                               char* __restrict__ ws) {
  __shared__ unsigned short lds[64 * 72];
  int bid = blockIdx.x;
  if (bid >= 240) {
    int* h = (int*)lds;
    int rbid = bid - 240;
    int t = threadIdx.x;
    if (t < NPAIR) h[t] = 0;
    __syncthreads();
    int r = rbid * 256 + t;
    const float* q = inp + (size_t)r * 144 + 128;
    float4 u0 = *(const float4*)(q + 0);
    float4 u1 = *(const float4*)(q + 4);
    float4 v0 = *(const float4*)(q + 8);
    float4 v1 = *(const float4*)(q + 12);
    int a0 = 0;
    if (u0.y > 0.5f) a0 = 1; if (u0.z > 0.5f) a0 = 2; if (u0.w > 0.5f) a0 = 3;
    if (u1.x > 0.5f) a0 = 4; if (u1.y > 0.5f) a0 = 5; if (u1.z > 0.5f) a0 = 6; if (u1.w > 0.5f) a0 = 7;
    int a1 = 0;
    if (v0.y > 0.5f) a1 = 1; if (v0.z > 0.5f) a1 = 2; if (v0.w > 0.5f) a1 = 3;
    if (v1.x > 0.5f) a1 = 4; if (v1.y > 0.5f) a1 = 5; if (v1.z > 0.5f) a1 = 6; if (v1.w > 0.5f) a1 = 7;
    int p = a0 * 8 + a1;
    ((int*)(ws + WS_PAIR))[r] = p;
    atomicAdd(&h[p], 1);
    __syncthreads();
    if (t < NPAIR) ((int*)(ws + WS_BH))[rbid * NPAIR + t] = h[t];
    return;
  }
  const float* src; char* dst; int I, O, lt, NT, KC;
  if (bid < 32)       { src = w00; dst = ws + WS_WF00; I = 64;  O = 256; lt = bid;       NT = 16; KC = 2; }
  else if (bid < 96)  { src = w01; dst = ws + WS_WF01; I = 256; O = 128; lt = bid - 32;  NT = 8;  KC = 8; }
  else if (bid < 128) { src = w1p; dst = ws + WS_WF1P; I = 64;  O = 256; lt = bid - 96;  NT = 16; KC = 2; }
  else if (bid < 224) { src = w1a; dst = ws + WS_WF1A; I = 384; O = 128; lt = bid - 128; NT = 8;  KC = 12; }
  else                { src = w1o; dst = ws + WS_WF1O; I = 128; O = 32;  lt = bid - 224; NT = 2;  KC = 4; }
  int tI = I >> 6;
  int tO = (O + 63) >> 6;
  int m   = lt / (tI * tO);
  int rem = lt % (tI * tO);
  int ib = rem / tO, ob = rem % tO;
  int tx = threadIdx.x & 63, ty = threadIdx.x >> 6;
  const float* s = src + (size_t)m * I * O;
  #pragma unroll 4
  for (int s4 = 0; s4 < 16; ++s4) {
    int li = s4 * 4 + ty;
    int o  = ob * 64 + tx;
    float v = (o < O) ? s[(size_t)(ib * 64 + li) * O + o] : 0.f;
    lds[li * 72 + tx] = f2bf(v);
  }
  __syncthreads();
  int lane = threadIdx.x & 63, u = threadIdx.x >> 6;
  int ln = lane & 15, lq = lane >> 4;
  #pragma unroll
  for (int it = 0; it < 2; ++it) {
    int fi  = it * 4 + u;
    int ntl = fi >> 1, kcl = fi & 1;
    int ntg = ob * 4 + ntl, kcg = ib * 2 + kcl;
    if (ntg * 16 < O) {
      bf16x8 f;
      #pragma unroll
      for (int j = 0; j < 8; ++j)
        f[j] = __builtin_bit_cast(__bf16, lds[(kcl * 32 + lq * 8 + j) * 72 + ntl * 16 + ln]);
      *(bf16x8*)(dst + (((size_t)(m * NT + ntg) * KC + kcg) * 64 + lane) * 16) = f;
    }
  }
}

// k_part: scan + scatter in ONE kernel. Parallelized: 4-way chunked partial
// sums (serial depth 128 -> 32), per-block prefix from chunk subtotals.
__global__ __launch_bounds__(256) void k_part(const int* __restrict__ bh,
                                              const int* __restrict__ pairArr,
                                              int* __restrict__ cnt,
                                              int* __restrict__ base,
                                              int* __restrict__ rowlist) {
  __shared__ int lbh[NBLK * NPAIR];
  __shared__ int part[4][NPAIR];   // chunk sums: blocks [c*32,(c+1)*32)
  __shared__ int loff[NPAIR];
  __shared__ int h[NPAIR];
  int tid = threadIdx.x, bid = blockIdx.x;
  const int4* s4 = (const int4*)bh;
  int4* d4 = (int4*)lbh;
  #pragma unroll
  for (int i = 0; i < 8; ++i) d4[tid + i * 256] = s4[tid + i * 256];
  if (tid < NPAIR) h[tid] = 0;
  __syncthreads();
  {
    int c = tid >> 6, p = tid & 63;   // all 256 threads active
    int s = 0;
    #pragma unroll
    for (int b = 0; b < 32; ++b) s += lbh[(c * 32 + b) * NPAIR + p];
    part[c][p] = s;
  }
  __syncthreads();
  if (tid < NPAIR) {
    int p = tid;
    int c = part[0][p] + part[1][p] + part[2][p] + part[3][p];
    // partial = sum over blocks < bid
    int partial = 0;
    int fullc = bid >> 5;
    #pragma unroll
    for (int c2 = 0; c2 < 4; ++c2) if (c2 < fullc) partial += part[c2][p];
    for (int b = fullc * 32; b < bid; ++b) partial += lbh[b * NPAIR + p];
    int ntp = (c + 31) >> 5;
    int z = ntp;
    #pragma unroll
    for (int d = 1; d < 64; d <<= 1) { int y = __shfl_up(z, d); if (p >= d) z += y; }
    int pbase = (z - ntp) * 32;
    loff[p] = pbase + partial;
    if (bid == 0) { cnt[p] = c; base[p] = pbase; }
  }
  __syncthreads();
  int r = bid * 256 + tid;
  int p = pairArr[r];
  int rank = atomicAdd(&h[p], 1);
  rowlist[loff[p] + rank] = r;
}

// Fused 5-layer routed MLP, per-pair persistent, 32-row tiles, 8 waves,
// grid 256 = 64 pairs x 4 slices. LDS 152K: W1a 96K @0 (staged ONCE),
// G 16K @98304, H1 16K @114688, HO 8K @131072, G2 8K @139264, xs 8K @147456.
// (Proven R19 structure: L1a G-half overlaps P2 with acc1a carried across
// barC; W1o hoisted; async input pipeline T14.)
__global__ __launch_bounds__(512, 1) void k_fused(
    const float* __restrict__ inp,
    const float* __restrict__ b00, const float* __restrict__ b01,
    const float* __restrict__ b1p, const float* __restrict__ b1a,
    const float* __restrict__ b1o,
    const char* __restrict__ ws, float* __restrict__ out)
{
  __shared__ char smem[155648];
  unsigned short* G   = (unsigned short*)(smem + 98304);
  unsigned short* H1m = (unsigned short*)(smem + 114688);
  unsigned short* HO  = (unsigned short*)(smem + 131072);
  unsigned short* G2  = (unsigned short*)(smem + 139264);
  char*           xs  = smem + 147456;

  int p     = blockIdx.x >> 2;
  int slice = blockIdx.x & 3;
  int e0 = p >> 3, e1 = p & 7;
  int cnt = ((const int*)(ws + WS_CNT))[p];
  int pbase = ((const int*)(ws + WS_BASE))[p];
  int ntp = (cnt + 31) >> 5;
  if (slice >= ntp) return;
  const int* rlbase = (const int*)(ws + WS_ROWLIST) + pbase;

  int tid  = threadIdx.x;
  // stage W1a[e1] (96KB) into LDS once, linear frag-major copy
  {
    const f32x4e* s1 = (const f32x4e*)(ws + WS_WF1A + (size_t)e1 * 98304);
    f32x4e* d1 = (f32x4e*)smem;
    #pragma unroll
    for (int i = 0; i < 12; ++i) d1[tid + i * 512] = s1[tid + i * 512];
  }

  int lane = tid & 63;
  int w    = tid >> 6;
  int ln = lane & 15, lq = lane >> 4;
  int kcol = lq * 8;

  // register weight sets (frag-major, lane-contiguous, loaded ONCE)
  bf16x8 w00f[2][2], w1pf[2][2];
  #pragma unroll
  for (int nt = 0; nt < 2; ++nt)
    #pragma unroll
    for (int kc = 0; kc < 2; ++kc) {
      w00f[nt][kc] = *(const bf16x8*)(ws + WS_WF00 + (size_t)e0 * 32768 +
                                      ((((w * 2 + nt) * 2 + kc) * 64 + lane) << 4));
      w1pf[nt][kc] = *(const bf16x8*)(ws + WS_WF1P + (size_t)e1 * 32768 +
                                      ((((w * 2 + nt) * 2 + kc) * 64 + lane) << 4));
    }
  bf16x8 wc[8];
  #pragma unroll
  for (int kc = 0; kc < 8; ++kc)
    wc[kc] = *(const bf16x8*)(ws + WS_WF01 + (size_t)e0 * 65536 +
                              (((w * 8 + kc) * 64 + lane) << 4));
  bf16x8 wo[4];
  if (w < 4) {
    #pragma unroll
    for (int kc = 0; kc < 4; ++kc)
      wo[kc] = *(const bf16x8*)(ws + WS_WF1O + (size_t)e1 * 8192 +
                                ((((w >> 1) * 4 + kc) * 64 + lane) << 4));
  }
  #pragma unroll
  for (int nt = 0; nt < 2; ++nt)
    #pragma unroll
    for (int kc = 0; kc < 2; ++kc) { KEEP(w00f[nt][kc]); KEEP(w1pf[nt][kc]); }
  #pragma unroll
  for (int kc = 0; kc < 8; ++kc) KEEP(wc[kc]);
  if (w < 4) {
    #pragma unroll
    for (int kc = 0; kc < 4; ++kc) KEEP(wo[kc]);
  }

  float bias00[2], bias1p[2];
  #pragma unroll
  for (int nt = 0; nt < 2; ++nt) {
    bias00[nt] = b00[e0 * 256 + w * 32 + nt * 16 + ln];
    bias1p[nt] = b1p[e1 * 256 + w * 32 + nt * 16 + ln];
  }
  float bias01 = b01[e0 * 128 + w * 16 + ln];
  float bias1a = b1a[e1 * 128 + w * 16 + ln];
  float bias1o = (w < 4) ? b1o[e1 * 32 + (w >> 1) * 16 + ln] : 0.f;

  const f32x4 z4 = {0.f, 0.f, 0.f, 0.f};
  int srow = tid >> 5, scol = tid & 31;    // staging: 16 rows/pass, 32 float4/row

  // ---- prologue: stage first tile directly into xs ----
  {
    int nr0 = min(32, cnt - slice * 32);
    const int* rl0 = rlbase + slice * 32;
    #pragma unroll
    for (int pass = 0; pass < 2; ++pass) {
      int row = pass * 16 + srow;
      int rg = (row < nr0) ? rl0[row] : -1;
      ushort4 v8 = {0, 0, 0, 0};
      if (rg >= 0) {
        f32x4e u = __builtin_nontemporal_load(
            (const f32x4e*)(inp + (size_t)rg * 144 + scol * 4));
        v8.x = f2bf(u.x); v8.y = f2bf(u.y); v8.z = f2bf(u.z); v8.w = f2bf(u.w);
      }
      int byte = (row * 256 + scol * 8) ^ ((row & 7) << 4);
      *(ushort4*)(xs + byte) = v8;
    }
  }
  __syncthreads();  // W1a staged + first xs ready

  for (int t = slice; t < ntp; t += 4) {
    int nr = min(32, cnt - t * 32);
    const int* rl = rlbase + t * 32;

    // ---- issue next tile's stage loads NOW (hidden under P1) ----
    int t2 = t + 4;
    bool hasNext = (t2 < ntp);
    f32x4e pre[2];
    #pragma unroll
    for (int pass = 0; pass < 2; ++pass) { pre[pass].x = 0; pre[pass].y = 0; pre[pass].z = 0; pre[pass].w = 0; }
    if (hasNext) {
      int nr2 = min(32, cnt - t2 * 32);
      const int* rl2 = rlbase + t2 * 32;
      #pragma unroll
      for (int pass = 0; pass < 2; ++pass) {
        int row = pass * 16 + srow;
        int rg = (row < nr2) ? rl2[row] : -1;
        if (rg >= 0)
          pre[pass] = __builtin_nontemporal_load(
              (const f32x4e*)(inp + (size_t)rg * 144 + scol * 4));
      }
      KEEP(pre[0]); KEEP(pre[1]);
    }

    // ===== P1: L00 -> H1, L1p -> G (reg weights, xs frags) =====
    bf16x8 axf[2][2][2];   // [half][mt][kc]
    #pragma unroll
    for (int half = 0; half < 2; ++half)
      #pragma unroll
      for (int mt = 0; mt < 2; ++mt)
        #pragma unroll
        for (int kc = 0; kc < 2; ++kc) {
          int row = mt * 16 + ln;
          int byte = (row * 256 + half * 128 + kc * 64 + lq * 16) ^ ((row & 7) << 4);
          axf[half][mt][kc] = *(const bf16x8*)(xs + byte);
        }
    #pragma unroll
    for (int nt = 0; nt < 2; ++nt) {
      int n = w * 32 + nt * 16 + ln;
      f32x4 acc0[2] = {z4, z4}, acc1[2] = {z4, z4};
      #pragma unroll
      for (int kc = 0; kc < 2; ++kc)
        #pragma unroll
        for (int mt = 0; mt < 2; ++mt) {
          acc0[mt] = __builtin_amdgcn_mfma_f32_16x16x32_bf16(axf[0][mt][kc], w00f[nt][kc], acc0[mt], 0, 0, 0);
          acc1[mt] = __builtin_amdgcn_mfma_f32_16x16x32_bf16(axf[1][mt][kc], w1pf[nt][kc], acc1[mt], 0, 0, 0);
        }
      #pragma unroll
      for (int mt = 0; mt < 2; ++mt)
        #pragma unroll
        for (int r = 0; r < 4; ++r) {
          int row = mt * 16 + lq * 4 + r;
          int sw = ((n << 1) ^ ((row & 7) << 4));
          H1m[(row * 512 + sw) >> 1] = f2bf(fmaxf(acc0[mt][r] + bias00[nt], 0.f));
          G  [(row * 512 + sw) >> 1] = f2bf(fmaxf(acc1[mt][r] + bias1p[nt], 0.f));
        }
    }
    __syncthreads();  // barB: H1,G ready; all xs reads done

    // ---- write next tile's xs from prefetched regs ----
    if (hasNext) {
      #pragma unroll
      for (int pass = 0; pass < 2; ++pass) {
        int row = pass * 16 + srow;
        ushort4 v8;
        v8.x = f2bf(pre[pass].x); v8.y = f2bf(pre[pass].y);
        v8.z = f2bf(pre[pass].z); v8.w = f2bf(pre[pass].w);
        int byte = (row * 256 + scol * 8) ^ ((row & 7) << 4);
        *(ushort4*)(xs + byte) = v8;
      }
    }

    // ===== P2 + P3g (overlapped): L01(H1) -> HO, and L1a G-half -> acc1a =====
    f32x4 acc1a[2] = {z4, z4};   // persists across barC
    {
      f32x4 acc[2] = {z4, z4};
      #pragma unroll
      for (int kc = 0; kc < 8; ++kc) {
        #pragma unroll
        for (int mt = 0; mt < 2; ++mt) {
          int row = mt * 16 + ln;
          bf16x8 afr = *(const bf16x8*)&H1m[(row * 512 + (((kc * 32 + kcol) << 1) ^ ((row & 7) << 4))) >> 1];
          acc[mt] = __builtin_amdgcn_mfma_f32_16x16x32_bf16(afr, wc[kc], acc[mt], 0, 0, 0);
        }
        {
          int kcg = kc + 4;
          bf16x8 bfr = *(const bf16x8*)(smem + (((w * 12 + kcg) * 64 + lane) << 4));
          #pragma unroll
          for (int mt = 0; mt < 2; ++mt) {
            int row = mt * 16 + ln;
            bf16x8 afr = *(const bf16x8*)&G[(row * 512 + (((kc * 32 + kcol) << 1) ^ ((row & 7) << 4))) >> 1];
            acc1a[mt] = __builtin_amdgcn_mfma_f32_16x16x32_bf16(afr, bfr, acc1a[mt], 0, 0, 0);
          }
        }
      }
      int n = w * 16 + ln;
      #pragma unroll
      for (int mt = 0; mt < 2; ++mt)
        #pragma unroll
        for (int r = 0; r < 4; ++r) {
          int row = mt * 16 + lq * 4 + r;
          float v = fmaxf(acc[mt][r] + bias01, 0.f);
          HO[(row * 256 + ((n << 1) ^ ((row & 7) << 4))) >> 1] = f2bf(v);
        }
    }
    __syncthreads();  // barC: HO ready

    // ===== P3h: L1a HO-half (kc<4) -> finish acc1a -> G2 =====
    {
      #pragma unroll
      for (int kc = 0; kc < 4; ++kc) {
        bf16x8 bfr = *(const bf16x8*)(smem + (((w * 12 + kc) * 64 + lane) << 4));
        #pragma unroll
        for (int mt = 0; mt < 2; ++mt) {
          int row = mt * 16 + ln;
          bf16x8 afr = *(const bf16x8*)&HO[(row * 256 + (((kc * 32 + kcol) << 1) ^ ((row & 7) << 4))) >> 1];
          acc1a[mt] = __builtin_amdgcn_mfma_f32_16x16x32_bf16(afr, bfr, acc1a[mt], 0, 0, 0);
        }
      }
      int n = w * 16 + ln;
      #pragma unroll
      for (int mt = 0; mt < 2; ++mt)
        #pragma unroll
        for (int r = 0; r < 4; ++r) {
          int row = mt * 16 + lq * 4 + r;
          float v = fmaxf(acc1a[mt][r] + bias1a, 0.f);
          G2[(row * 256 + ((n << 1) ^ ((row & 7) << 4))) >> 1] = f2bf(v);
        }
    }
    __syncthreads();  // barD: G2 ready; all G/H1/HO reads done

    // ===== P4 (waves 0..3): L1o (G2 @ reg W1o) -> out (NT store) =====
    if (w < 4) {
      int mt = w & 1;
      int n  = (w >> 1) * 16 + ln;
      f32x4 acc = z4;
      #pragma unroll
      for (int kc = 0; kc < 4; ++kc) {
        int row = mt * 16 + ln;
        bf16x8 afr = *(const bf16x8*)&G2[(row * 256 + (((kc * 32 + kcol) << 1) ^ ((row & 7) << 4))) >> 1];
        acc = __builtin_amdgcn_mfma_f32_16x16x32_bf16(afr, wo[kc], acc, 0, 0, 0);
      }
      #pragma unroll
      for (int r = 0; r < 4; ++r) {
        int row = mt * 16 + lq * 4 + r;
        if (row < nr) {
          int rg = rl[row];
          __builtin_nontemporal_store(acc[r] + bias1o, &out[(size_t)rg * 32 + n]);
        }
      }
    }
  }
}

extern "C" void kernel_launch(void* const* d_in, const int* in_sizes, int n_in,
                              void* d_out, int out_size, void* d_ws, size_t ws_size,
                              hipStream_t stream) {
  const float* inp = (const float*)d_in[0];
  const float* w00 = (const float*)d_in[1];
  const float* b00 = (const float*)d_in[2];
  const float* w01 = (const float*)d_in[3];
  const float* b01 = (const float*)d_in[4];
  const float* w1p = (const float*)d_in[5];
  const float* b1p = (const float*)d_in[6];
  const float* w1a = (const float*)d_in[7];
  const float* b1a = (const float*)d_in[8];
  const float* w1o = (const float*)d_in[9];
  const float* b1o = (const float*)d_in[10];
  char*  ws  = (char*)d_ws;
  float* out = (float*)d_out;

  k_combo<<<368, 256, 0, stream>>>(w00, w01, w1p, w1a, w1o, inp, ws);
  k_part<<<NBLK, 256, 0, stream>>>((const int*)(ws + WS_BH),
                                   (const int*)(ws + WS_PAIR),
                                   (int*)(ws + WS_CNT), (int*)(ws + WS_BASE),
                                   (int*)(ws + WS_ROWLIST));
  k_fused<<<256, 512, 0, stream>>>(inp, b00, b01, b1p, b1a, b1o, ws, out);
}